// Round 1
// baseline (194.525 us; speedup 1.0000x reference)
//
#include <hip/hip_runtime.h>
#include <hip/hip_bf16.h>

// Dead-code analysis of the reference:
//   - Output = (pred, act), both functions of last = latent[:, -1, :].
//   - latent = _mha(h, ctx) with a SINGLE key/value token (ctx is (B,1,D)).
//     softmax over a length-1 axis == 1.0, so attention output == v,
//     independent of the queries -> independent of h -> the entire 4-layer
//     encoder is dead code.
//   - Live chain per batch row b:
//       ctxp = context[b] @ ctx_w + ctx_b                  (512)
//       v    = ctxp @ ca_in_w[:, 1024:1536] + ca_in_b[1024:]  (512)
//       last = v @ ca_out_w + ca_out_b                     (512)
//       pred = last @ spec_pred_w[sid[b]] + spec_pred_b[sid[b]]  (64)
//       act  = last @ spec_act_w[sid[b]]  + spec_act_b[sid[b]]   (64)
//   - Rows are independent -> one block per row, whole chain fused.

#define D_MODEL 512
#define HOUT 64

__global__ __launch_bounds__(512) void HivemindAgent_tail_kernel(
    const float* __restrict__ context,   // (64, 2)
    const int*   __restrict__ sids,      // (64,)
    const float* __restrict__ ctx_w,     // (2, 512)
    const float* __restrict__ ctx_b,     // (512,)
    const float* __restrict__ ca_in_w,   // (512, 1536) row-major
    const float* __restrict__ ca_in_b,   // (1536,)
    const float* __restrict__ ca_out_w,  // (512, 512)
    const float* __restrict__ ca_out_b,  // (512,)
    const float* __restrict__ pw,        // (4, 512, 64)
    const float* __restrict__ pb,        // (4, 64)
    const float* __restrict__ aw,        // (4, 512, 64)
    const float* __restrict__ ab,        // (4, 64)
    float* __restrict__ out)             // pred (64*64) | act (64*64)
{
    __shared__ float bufA[D_MODEL];
    __shared__ float bufB[D_MODEL];

    const int b = blockIdx.x;
    const int t = threadIdx.x;

    // Stage 1: ctxp = context[b] @ ctx_w + ctx_b
    const float c0 = context[2 * b + 0];
    const float c1 = context[2 * b + 1];
    bufA[t] = c0 * ctx_w[t] + c1 * ctx_w[D_MODEL + t] + ctx_b[t];
    __syncthreads();

    // Stage 2: v[t] = sum_k ctxp[k] * ca_in_w[k][1024 + t] + ca_in_b[1024 + t]
    {
        const float* W = ca_in_w + 2 * D_MODEL + t;  // column (1024 + t)
        float acc = ca_in_b[2 * D_MODEL + t];
        #pragma unroll 8
        for (int k = 0; k < D_MODEL; ++k)
            acc += bufA[k] * W[k * (3 * D_MODEL)];
        bufB[t] = acc;
    }
    __syncthreads();

    // Stage 3: last[t] = sum_k v[k] * ca_out_w[k][t] + ca_out_b[t]
    {
        const float* W = ca_out_w + t;
        float acc = ca_out_b[t];
        #pragma unroll 8
        for (int k = 0; k < D_MODEL; ++k)
            acc += bufB[k] * W[k * D_MODEL];
        bufA[t] = acc;   // bufA now holds `last` (safe: no reads of bufA here)
    }
    __syncthreads();

    // Stage 4: specialist heads. 128 threads: t<64 -> pred, t>=64 -> act.
    if (t < 2 * HOUT) {
        const int   s   = sids[b];
        const int   o   = t & (HOUT - 1);
        const bool  isp = (t < HOUT);
        const float* W  = (isp ? pw : aw) + (size_t)s * D_MODEL * HOUT + o;
        float acc       = (isp ? pb : ab)[s * HOUT + o];
        #pragma unroll 8
        for (int k = 0; k < D_MODEL; ++k)
            acc += bufA[k] * W[k * HOUT];
        out[(isp ? 0 : 64 * HOUT) + b * HOUT + o] = acc;
    }
}

extern "C" void kernel_launch(void* const* d_in, const int* in_sizes, int n_in,
                              void* d_out, int out_size, void* d_ws, size_t ws_size,
                              hipStream_t stream) {
    // setup_inputs() dict order:
    //  0 x | 1 context | 2 specialist_ids | 3 emb_table | 4 enc_in_w | 5 enc_in_b
    //  6 enc_out_w | 7 enc_out_b | 8 ln1_g | 9 ln1_b | 10 lin1_w | 11 lin1_b
    // 12 lin2_w | 13 lin2_b | 14 ln2_g | 15 ln2_b | 16 ctx_w | 17 ctx_b
    // 18 ca_in_w | 19 ca_in_b | 20 ca_out_w | 21 ca_out_b
    // 22 spec_pred_w | 23 spec_pred_b | 24 spec_act_w | 25 spec_act_b
    const float* context  = (const float*)d_in[1];
    const int*   sids     = (const int*)  d_in[2];
    const float* ctx_w    = (const float*)d_in[16];
    const float* ctx_b    = (const float*)d_in[17];
    const float* ca_in_w  = (const float*)d_in[18];
    const float* ca_in_b  = (const float*)d_in[19];
    const float* ca_out_w = (const float*)d_in[20];
    const float* ca_out_b = (const float*)d_in[21];
    const float* pw       = (const float*)d_in[22];
    const float* pb       = (const float*)d_in[23];
    const float* aw       = (const float*)d_in[24];
    const float* ab       = (const float*)d_in[25];
    float*       out      = (float*)d_out;

    HivemindAgent_tail_kernel<<<64, 512, 0, stream>>>(
        context, sids, ctx_w, ctx_b, ca_in_w, ca_in_b,
        ca_out_w, ca_out_b, pw, pb, aw, ab, out);
}

// Round 5
// 145.787 us; speedup vs baseline: 1.3343x; 1.3343x over previous
//
#include <hip/hip_runtime.h>
#include <hip/hip_bf16.h>

// Live computation (see round-0 analysis: length-1-softmax kills the encoder):
//   last[b] = (context[b] @ ctx_w + ctx_b) @ Wv + bv) @ Wo + bo
// context is (B,2) => rank-2 fold:
//   last[b] = c0*m0 + c1*m1 + f
//     m_i = (ctx_w[i] @ Wv) @ Wo                (512-vector, i=0,1)
//     f   = ((ctx_b @ Wv + bv) @ Wo) + bo      (512-vector)
// Heads fold (4 specialists x 2 heads):
//   P0/P1/Pf[s,h] = {m0,m1,f} @ Whead[s,h] (+bias into Pf)
//   out[b,h] = c0*P0[sid,h] + c1*P1[sid,h] + Pf[sid,h]
// => each weight byte read exactly once. 3 kernels = 3 pipeline barriers.
//
// Wv = ca_in_w[:, 1024:1536] (row stride 1536), bv = ca_in_b[1024:]
// Wo = ca_out_w (512x512), bo = ca_out_b

#define NB1 64
#define CHUNK1 8    // 512 / NB1
#define NB2 32
#define CHUNK2 16   // 512 / NB2

// K1: partial r0/r1/e over a CHUNK1-row slab of Wv.
__global__ __launch_bounds__(512) void hv_k1(
    const float* __restrict__ ctx_w,    // (2,512)
    const float* __restrict__ ctx_b,    // (512,)
    const float* __restrict__ ca_in_w,  // (512,1536)
    float* __restrict__ pA)             // (NB1,3,512)
{
    const int j = blockIdx.x, t = threadIdx.x;
    const int k0 = j * CHUNK1;
    const float* W = ca_in_w + (size_t)k0 * 1536 + 1024 + t;
    float a0 = 0.f, a1 = 0.f, a2 = 0.f;
    #pragma unroll
    for (int k = 0; k < CHUNK1; ++k) {
        const float w  = W[k * 1536];          // coalesced row read
        a0 += ctx_w[      k0 + k] * w;         // block-uniform scalars
        a1 += ctx_w[512 + k0 + k] * w;
        a2 += ctx_b[      k0 + k] * w;
    }
    pA[(j * 3 + 0) * 512 + t] = a0;
    pA[(j * 3 + 1) * 512 + t] = a1;
    pA[(j * 3 + 2) * 512 + t] = a2;
}

// K2: reduce r for this block's k-chunk, then partial m0/m1/f over Wo slab.
__global__ __launch_bounds__(512) void hv_k2(
    const float* __restrict__ pA,        // (NB1,3,512)
    const float* __restrict__ ca_in_b,   // (1536,)
    const float* __restrict__ ca_out_w,  // (512,512)
    float* __restrict__ pB)              // (NB2,3,512)
{
    __shared__ float r[3][CHUNK2];
    const int j = blockIdx.x, t = threadIdx.x;
    const int k0 = j * CHUNK2;
    if (t < 3 * CHUNK2) {
        const int v = t / CHUNK2, k = t % CHUNK2;
        float s = 0.f;
        for (int jj = 0; jj < NB1; ++jj)
            s += pA[(jj * 3 + v) * 512 + k0 + k];
        if (v == 2) s += ca_in_b[1024 + k0 + k];   // bv folds into e
        r[v][k] = s;
    }
    __syncthreads();
    const float* W = ca_out_w + (size_t)k0 * 512 + t;
    float a0 = 0.f, a1 = 0.f, a2 = 0.f;
    #pragma unroll
    for (int k = 0; k < CHUNK2; ++k) {
        const float w = W[k * 512];            // coalesced row read
        a0 += r[0][k] * w;                     // LDS broadcast (free)
        a1 += r[1][k] * w;
        a2 += r[2][k] * w;
    }
    pB[(j * 3 + 0) * 512 + t] = a0;
    pB[(j * 3 + 1) * 512 + t] = a1;
    pB[(j * 3 + 2) * 512 + t] = a2;
}

// K3: one block per (specialist s, head h). Reduce m0/m1/f, fold through the
// head weights, scatter outputs for every b with sid[b]==s.
__global__ __launch_bounds__(512) void hv_k3(
    const float* __restrict__ pB,        // (NB2,3,512)
    const float* __restrict__ ca_out_b,  // (512,)
    const float* __restrict__ pw, const float* __restrict__ pb,
    const float* __restrict__ aw, const float* __restrict__ ab,
    const float* __restrict__ context,   // (64,2)
    const int*   __restrict__ sids,      // (64,)
    float* __restrict__ out)             // pred(64*64) | act(64*64)
{
    __shared__ float m[3][512];
    __shared__ float red[3][8][64];
    const int s = blockIdx.x >> 1, h = blockIdx.x & 1;
    const int t = threadIdx.x;

    // reduce partials -> m0, m1, f  (bo folds into f)
    {
        float s0 = 0.f, s1 = 0.f, s2 = 0.f;
        for (int jj = 0; jj < NB2; ++jj) {
            s0 += pB[(jj * 3 + 0) * 512 + t];
            s1 += pB[(jj * 3 + 1) * 512 + t];
            s2 += pB[(jj * 3 + 2) * 512 + t];
        }
        m[0][t] = s0; m[1][t] = s1; m[2][t] = s2 + ca_out_b[t];
    }
    __syncthreads();

    // head matvec: P[o] = sum_d m[d] * W[d][o], split d into 8 chunks of 64
    const float* W  = (h ? aw : pw) + (size_t)s * 512 * 64;
    const float* Bv = (h ? ab : pb) + s * 64;
    const int o = t & 63, c = t >> 6;
    const float* Wc = W + (size_t)c * 64 * 64 + o;
    float p0 = 0.f, p1 = 0.f, p2 = 0.f;
    #pragma unroll 8
    for (int d = 0; d < 64; ++d) {
        const float w  = Wc[d * 64];           // coalesced across o
        const int   dd = c * 64 + d;
        p0 += m[0][dd] * w; p1 += m[1][dd] * w; p2 += m[2][dd] * w;
    }
    red[0][c][o] = p0; red[1][c][o] = p1; red[2][c][o] = p2;
    __syncthreads();

    if (t < 64) {
        float P0 = 0.f, P1 = 0.f, P2 = Bv[t];
        #pragma unroll
        for (int c2 = 0; c2 < 8; ++c2) {
            P0 += red[0][c2][t]; P1 += red[1][c2][t]; P2 += red[2][c2][t];
        }
        for (int b = 0; b < 64; ++b) {
            if (sids[b] == s) {
                const float c0 = context[2 * b], c1 = context[2 * b + 1];
                out[h * 4096 + b * 64 + t] = c0 * P0 + c1 * P1 + P2;
            }
        }
    }
}

extern "C" void kernel_launch(void* const* d_in, const int* in_sizes, int n_in,
                              void* d_out, int out_size, void* d_ws, size_t ws_size,
                              hipStream_t stream) {
    const float* context  = (const float*)d_in[1];
    const int*   sids     = (const int*)  d_in[2];
    const float* ctx_w    = (const float*)d_in[16];
    const float* ctx_b    = (const float*)d_in[17];
    const float* ca_in_w  = (const float*)d_in[18];
    const float* ca_in_b  = (const float*)d_in[19];
    const float* ca_out_w = (const float*)d_in[20];
    const float* ca_out_b = (const float*)d_in[21];
    const float* pw       = (const float*)d_in[22];
    const float* pb       = (const float*)d_in[23];
    const float* aw       = (const float*)d_in[24];
    const float* ab       = (const float*)d_in[25];
    float*       out      = (float*)d_out;

    float* pA = (float*)d_ws;                       // NB1*3*512 = 98304 floats
    float* pB = pA + NB1 * 3 * 512;                 // NB2*3*512 = 49152 floats

    hv_k1<<<NB1, 512, 0, stream>>>(ctx_w, ctx_b, ca_in_w, pA);
    hv_k2<<<NB2, 512, 0, stream>>>(pA, ca_in_b, ca_out_w, pB);
    hv_k3<<<8,   512, 0, stream>>>(pB, ca_out_b, pw, pb, aw, ab,
                                   context, sids, out);
}